// Round 10
// baseline (309.396 us; speedup 1.0000x reference)
//
#include <hip/hip_runtime.h>
#include <hip/hip_bf16.h>

#define NNODES   524288
#define NGRAPHS  4096
#define TPB      4     // 64-node tiles per block; grid = NNODES/(64*TPB) = 2048
#define GS       12    // head LDS row stride (floats)

typedef __attribute__((ext_vector_type(8)))  short short8;
typedef __attribute__((ext_vector_type(4)))  float f32x4;
typedef __attribute__((ext_vector_type(16))) float f32x16;

static __device__ __forceinline__ unsigned short f2bf(float f) {
    __hip_bfloat16 h = __float2bfloat16(f);
    return *reinterpret_cast<unsigned short*>(&h);
}

// swizzled LDS offset (shorts): node-row 128 shorts, 16B chunks XOR-permuted
static __device__ __forceinline__ int swz(int node, int chunk) {
    return node * 128 + ((chunk ^ (node & 15)) << 3);
}

// ---- one-time: frag-ordered bf16 weights.
// wF[((ofg*8+ks)*64+ln)*8+j] = w[k][of], k=ks*16+(ln>>5)*8+j, of=ofg*32+(ln&31)
// -> phi's weight loads are fully-coalesced 1KB dwordx4 streams.
// w0p[of*16+k]: k<4 = w0[k][of], k==4 = b0[of] (bias via B[k=4]=1.0), else 0 ----
__global__ __launch_bounds__(256) void prep_weights(
        const float* __restrict__ w0, const float* __restrict__ b0,
        const float* __restrict__ w1, const float* __restrict__ w2,
        unsigned short* __restrict__ w0p, unsigned short* __restrict__ w1F,
        unsigned short* __restrict__ w2F) {
    int e = blockIdx.x * 256 + threadIdx.x;
    if (e < 32768) {
        const int i   = e & 16383;
        const int j   = i & 7;
        const int ln  = (i >> 3) & 63;
        const int ks  = (i >> 9) & 7;
        const int ofg = i >> 12;
        const int k   = ks * 16 + (ln >> 5) * 8 + j;
        const int of  = ofg * 32 + (ln & 31);
        const float v = (e < 16384) ? w1[k * 128 + of] : w2[k * 128 + of];
        (e < 16384 ? w1F : w2F)[i] = f2bf(v);
    } else if (e < 34816) {
        int i = e - 32768;                 // w0p[128][16]
        int of = i >> 4, k = i & 15;
        unsigned short v = 0;
        if (k < 4)       v = f2bf(w0[k * 128 + of]);
        else if (k == 4) v = f2bf(b0[of]);
        w0p[i] = v;
    }
}

// ---- fused phi MLP: 2-wave blocks, of-split (each wave owns 64 output feats),
//      combined regs ~128/wave -> 4 waves/SIMD; frag-ordered global weights ----
__global__ __launch_bounds__(128, 4) void phi_kernel(
        const float* __restrict__ x, const int* __restrict__ batch,
        const unsigned short* __restrict__ w0p,
        const unsigned short* __restrict__ w1F, const float* __restrict__ b1,
        const unsigned short* __restrict__ w2F, const float* __restrict__ b2,
        float* __restrict__ g) {
    __shared__ __align__(16) unsigned short hb[64 * 128];   // 16 KB shared by 2 waves
    const int tid  = threadIdx.x;
    const int lane = tid & 63;
    const int wv   = tid >> 6;       // wave 0: ofs 0..63, wave 1: ofs 64..127
    const int l31  = lane & 31;
    const int h    = lane >> 5;

    // per-wave of-half weights for layer 1 (+ b2 epilogue biases)
    short8 w0r[2];
    #pragma unroll
    for (int mt = 0; mt < 2; ++mt)
        w0r[mt] = *reinterpret_cast<const short8*>(
            w0p + ((wv*2 + mt)*32 + l31)*16 + h*8);
    float b2v[2];
    #pragma unroll
    for (int ntc = 0; ntc < 2; ++ntc) b2v[ntc] = b2[(wv*2 + ntc)*32 + l31];

    f32x16 acc[4];

    // swapped-C writeback (col=node=l31, row=of) -> swizzled hb, packed b64
    auto writeback = [&](const float* __restrict__ bias) {
        #pragma unroll
        for (int mt = 0; mt < 2; ++mt) {
            #pragma unroll
            for (int q = 0; q < 4; ++q) {
                float4 bv = make_float4(0.f, 0.f, 0.f, 0.f);
                if (bias)
                    bv = *reinterpret_cast<const float4*>(
                        bias + (wv*2 + mt)*32 + 8*q + 4*h);
                #pragma unroll
                for (int nt = 0; nt < 2; ++nt) {
                    const int node = nt*32 + l31;
                    const f32x16 A = acc[mt*2 + nt];
                    ushort4 s;
                    s.x = f2bf(fmaxf(A[4*q+0] + bv.x, 0.f));
                    s.y = f2bf(fmaxf(A[4*q+1] + bv.y, 0.f));
                    s.z = f2bf(fmaxf(A[4*q+2] + bv.z, 0.f));
                    s.w = f2bf(fmaxf(A[4*q+3] + bv.w, 0.f));
                    *reinterpret_cast<ushort4*>(
                        &hb[swz(node, (wv*2 + mt)*4 + q) + h*4]) = s;
                }
            }
        }
    };

    #pragma unroll 1
    for (int t = 0; t < TPB; ++t) {
        const int n0 = (blockIdx.x * TPB + t) * 64;

        const int gi = batch[n0 + lane];
        const int gp = __shfl_up(gi, 1);
        const unsigned long long mask = __ballot((lane == 0) || (gi != gp));

        // ---- layer 1 (swapped: A = w0r of-half, B = x rows; b0 via k=4) ----
        #pragma unroll
        for (int i = 0; i < 4; ++i) acc[i] = (f32x16){};
        #pragma unroll
        for (int nt = 0; nt < 2; ++nt) {
            const float4 xv = *reinterpret_cast<const float4*>(
                x + (size_t)(n0 + nt*32 + l31) * 4);
            short8 v = (short8){0,0,0,0,0,0,0,0};
            if (h == 0) {
                v[0] = (short)f2bf(xv.x); v[1] = (short)f2bf(xv.y);
                v[2] = (short)f2bf(xv.z); v[3] = (short)f2bf(xv.w);
                v[4] = (short)0x3F80;   // 1.0 -> + b0 row
            }
            #pragma unroll
            for (int mt = 0; mt < 2; ++mt)
                acc[mt*2 + nt] = __builtin_amdgcn_mfma_f32_32x32x16_bf16(
                    w0r[mt], v, acc[mt*2 + nt], 0, 0, 0);
        }
        writeback(nullptr);          // h0 (relu; b0 folded)
        __syncthreads();             // h0 complete before any L2 read

        // ---- layer 2 (swapped: A = w1 frags [of-half], B = h0 node rows) ----
        #pragma unroll
        for (int i = 0; i < 4; ++i) acc[i] = (f32x16){};
        #pragma unroll
        for (int ks = 0; ks < 8; ++ks) {
            short8 wf[2], bfr[2];
            #pragma unroll
            for (int mt = 0; mt < 2; ++mt)
                wf[mt] = *reinterpret_cast<const short8*>(
                    w1F + (((wv*2 + mt)*8 + ks)*64 + lane)*8);
            #pragma unroll
            for (int nt = 0; nt < 2; ++nt)
                bfr[nt] = *reinterpret_cast<const short8*>(
                    &hb[swz(nt*32 + l31, ks*2 + h)]);
            #pragma unroll
            for (int mt = 0; mt < 2; ++mt)
                #pragma unroll
                for (int nt = 0; nt < 2; ++nt)
                    acc[mt*2 + nt] = __builtin_amdgcn_mfma_f32_32x32x16_bf16(
                        wf[mt], bfr[nt], acc[mt*2 + nt], 0, 0, 0);
        }
        __syncthreads();             // all h0 reads done before h1 overwrite
        writeback(b1);               // h1 (bias + relu)
        __syncthreads();             // h1 complete before any L3 read

        // ---- layer 3 (normal: A = h1 node rows, B = w2 frags [of-half]) ----
        #pragma unroll
        for (int i = 0; i < 4; ++i) acc[i] = (f32x16){};
        #pragma unroll
        for (int ks = 0; ks < 8; ++ks) {
            short8 afr[2], wf[2];
            #pragma unroll
            for (int mtn = 0; mtn < 2; ++mtn)
                afr[mtn] = *reinterpret_cast<const short8*>(
                    &hb[swz(mtn*32 + l31, ks*2 + h)]);
            #pragma unroll
            for (int ntc = 0; ntc < 2; ++ntc)
                wf[ntc] = *reinterpret_cast<const short8*>(
                    w2F + (((wv*2 + ntc)*8 + ks)*64 + lane)*8);
            #pragma unroll
            for (int mtn = 0; mtn < 2; ++mtn)
                #pragma unroll
                for (int ntc = 0; ntc < 2; ++ntc)
                    acc[mtn*2 + ntc] = __builtin_amdgcn_mfma_f32_32x32x16_bf16(
                        afr[mtn], wf[ntc], acc[mtn*2 + ntc], 0, 0, 0);
        }

        // ---- epilogue: register segmented sum. C: col=of, row=node ----
        unsigned long long rem = mask & (mask - 1);
        int s = 0;
        while (true) {
            const int e = rem ? (int)__builtin_ctzll(rem) : 64;
            const int grun = __shfl(gi, s);
            const float cnt = (float)(e - s);
            float* gdst = g + (size_t)grun * 128;
            #pragma unroll
            for (int ntc = 0; ntc < 2; ++ntc) {
                float val = 0.f;
                #pragma unroll
                for (int mtn = 0; mtn < 2; ++mtn) {
                    const f32x16 A = acc[mtn*2 + ntc];
                    #pragma unroll
                    for (int r = 0; r < 16; ++r) {
                        const int node = mtn*32 + (r & 3) + 8*(r >> 2) + 4*h;
                        const float inc = (node >= s && node < e) ? 1.f : 0.f;
                        val = fmaf(A[r], inc, val);
                    }
                }
                val += __shfl_xor(val, 32);
                if (h == 0)
                    atomicAdd(gdst + (wv*2 + ntc)*32 + l31,
                              fmaf(cnt, b2v[ntc], val));
            }
            if (!rem) break;
            s = e;
            rem &= rem - 1;
        }
        __syncthreads();             // sibling's L3 reads done before next h0 write
    }
}

// ---- F head: fused 3 layers, 8 graphs/block, 512 blocks ----
__global__ __launch_bounds__(256) void head_kernel(
        const float* __restrict__ g,
        const float* __restrict__ fw0, const float* __restrict__ fb0,
        const float* __restrict__ fw1, const float* __restrict__ fb1,
        const float* __restrict__ fw2, const float* __restrict__ fb2,
        float* __restrict__ out) {
    __shared__ float gS[128 * GS];
    __shared__ float h1T[256 * GS];
    __shared__ float red[4][16];
    const int tid = threadIdx.x;
    const int g0  = blockIdx.x * 8;

    {
        const int gr = tid >> 5, k0 = (tid & 31) * 4;
        const float4 v = *reinterpret_cast<const float4*>(
            g + (size_t)(g0 + gr) * 128 + k0);
        gS[(k0+0)*GS + gr] = v.x; gS[(k0+1)*GS + gr] = v.y;
        gS[(k0+2)*GS + gr] = v.z; gS[(k0+3)*GS + gr] = v.w;
    }
    __syncthreads();

    float a1[8];
    #pragma unroll
    for (int i = 0; i < 8; ++i) a1[i] = 0.f;
    #pragma unroll 4
    for (int k = 0; k < 128; ++k) {
        const float w = fw0[k * 256 + tid];
        const f32x4 v0 = *reinterpret_cast<const f32x4*>(&gS[k*GS]);
        const f32x4 v1 = *reinterpret_cast<const f32x4*>(&gS[k*GS + 4]);
        #pragma unroll
        for (int j = 0; j < 4; ++j) {
            a1[j]     = fmaf(v0[j], w, a1[j]);
            a1[4 + j] = fmaf(v1[j], w, a1[4 + j]);
        }
    }
    {
        const float bb = fb0[tid];
        f32x4 s0, s1;
        #pragma unroll
        for (int j = 0; j < 4; ++j) {
            s0[j] = fmaxf(a1[j] + bb, 0.f);
            s1[j] = fmaxf(a1[4 + j] + bb, 0.f);
        }
        *reinterpret_cast<f32x4*>(&h1T[tid*GS])     = s0;
        *reinterpret_cast<f32x4*>(&h1T[tid*GS + 4]) = s1;
    }
    __syncthreads();

    float a2[8];
    #pragma unroll
    for (int i = 0; i < 8; ++i) a2[i] = 0.f;
    #pragma unroll 4
    for (int k = 0; k < 256; ++k) {
        const float w = fw1[k * 256 + tid];
        const f32x4 v0 = *reinterpret_cast<const f32x4*>(&h1T[k*GS]);
        const f32x4 v1 = *reinterpret_cast<const f32x4*>(&h1T[k*GS + 4]);
        #pragma unroll
        for (int j = 0; j < 4; ++j) {
            a2[j]     = fmaf(v0[j], w, a2[j]);
            a2[4 + j] = fmaf(v1[j], w, a2[4 + j]);
        }
    }

    float p[16];
    {
        const float bb  = fb1[tid];
        const float w2a = fw2[tid*2 + 0];
        const float w2b = fw2[tid*2 + 1];
        #pragma unroll
        for (int i = 0; i < 8; ++i) {
            const float h2 = fmaxf(a2[i] + bb, 0.f);
            p[i*2 + 0] = h2 * w2a;
            p[i*2 + 1] = h2 * w2b;
        }
    }
    #pragma unroll
    for (int i = 0; i < 16; ++i) {
        float v = p[i];
        v += __shfl_xor(v, 32); v += __shfl_xor(v, 16); v += __shfl_xor(v, 8);
        v += __shfl_xor(v, 4);  v += __shfl_xor(v, 2);  v += __shfl_xor(v, 1);
        p[i] = v;
    }
    if ((tid & 63) == 0) {
        #pragma unroll
        for (int i = 0; i < 16; ++i) red[tid >> 6][i] = p[i];
    }
    __syncthreads();
    if (tid < 16)
        out[g0*2 + tid] = red[0][tid] + red[1][tid] + red[2][tid] + red[3][tid]
                        + fb2[tid & 1];
}

extern "C" void kernel_launch(void* const* d_in, const int* in_sizes, int n_in,
                              void* d_out, int out_size, void* d_ws, size_t ws_size,
                              hipStream_t stream) {
    const float* x   = (const float*)d_in[0];
    // d_in[1] edge_index: mathematically dead (update() ignores aggr_out) — never read
    const int*   batch = (const int*)d_in[2];
    const float* w0  = (const float*)d_in[3];
    const float* b0  = (const float*)d_in[4];
    const float* w1  = (const float*)d_in[5];
    const float* b1  = (const float*)d_in[6];
    const float* w2  = (const float*)d_in[7];
    const float* b2  = (const float*)d_in[8];
    const float* fw0 = (const float*)d_in[9];
    const float* fb0 = (const float*)d_in[10];
    const float* fw1 = (const float*)d_in[11];
    const float* fb1 = (const float*)d_in[12];
    const float* fw2 = (const float*)d_in[13];
    const float* fb2 = (const float*)d_in[14];
    float* out = (float*)d_out;

    float* g = (float*)d_ws;                                        // 2 MB
    unsigned short* w1F = (unsigned short*)((char*)d_ws + (size_t)NGRAPHS * 128 * 4);
    unsigned short* w2F = w1F + 128 * 128;
    unsigned short* w0p = w2F + 128 * 128;                          // 4 KB

    (void)hipMemsetAsync(g, 0, (size_t)NGRAPHS * 128 * sizeof(float), stream);
    prep_weights<<<136, 256, 0, stream>>>(w0, b0, w1, w2, w0p, w1F, w2F);
    phi_kernel<<<NNODES / (64 * TPB), 128, 0, stream>>>(
        x, batch, w0p, w1F, b1, w2F, b2, g);
    head_kernel<<<NGRAPHS / 8, 256, 0, stream>>>(g, fw0, fb0, fw1, fb1, fw2, fb2, out);
}